// Round 7
// baseline (293.209 us; speedup 1.0000x reference)
//
#include <hip/hip_runtime.h>

// Problem constants (from reference): E=1024, H=16, D=64, B=32, S=1024.
// ALGEBRA: softmax over a length-1 key axis == 1.0 exactly, so attention
// collapses: attn_out[b,:] = Wo @ (Wv @ (W_heat @ heat[b] + b_heat) + bv) + bo
// (independent of s; the img projection / Q / K path is dead code).
// Final: out[b,s,:] = LayerNorm(img_feat[b,s,:] + a[b,:]) * gamma + beta.
// All tensors fp32. Vanilla HIP types / plain loads only.
//
// LN ledger: block-per-row (r0) = wave-per-row serial (r3) = fenced pipeline
// (r6) = ~82 us @ 3.3 TB/s logical; split stats/apply (r5) worse. Occupancy
// 9%..34% -> no effect; store entanglement refuted (r0). Remaining suspect:
// the 64-lane-per-row reduce shape (12 dependent ds_permute per 4 KB row).
// This round: 4 rows per wave, 16 LANES PER ROW -> butterfly is 4 strides
// within 16-lane groups (8 shfls per 4 rows, 6x less cross-lane work), all
// 16 img loads issued as one independent batch, y=img+a held in registers
// so apply needs no re-read; stores only at wave end.

#define E_DIM 1024
#define B_DIM 32
#define S_DIM 1024

// ---- GEMV stage: y[b,e] = dot(W[e,:], x[b,:]) + bias[e] -------------------
// (unchanged from the passing round-3..6 version)
__global__ __launch_bounds__(256) void gemv_xlds(
        const float* __restrict__ W,    // [E,E] row-major
        const float* __restrict__ bias, // [E]
        const float* __restrict__ x,    // [B,E]
        float* __restrict__ y) {        // [B,E]
    __shared__ float4 xs[8 * 256];       // 8 batches x 1024 f32 = 32 KiB
    const int t = threadIdx.x;
    const int rg = blockIdx.x & 255;     // row group -> rows [rg*4, rg*4+4)
    const int bq = blockIdx.x >> 8;      // batch quarter -> batches [bq*8, ..+8)

    const float4* x4 = reinterpret_cast<const float4*>(x) + (size_t)bq * 8 * 256;
    #pragma unroll
    for (int i = 0; i < 8; ++i)
        xs[i * 256 + t] = x4[i * 256 + t];
    __syncthreads();

    const int wave = t >> 6;
    const int lane = t & 63;
    const int e = rg * 4 + wave;

    const float4* w4 = reinterpret_cast<const float4*>(W + (size_t)e * E_DIM);
    float4 w0 = w4[lane];
    float4 w1 = w4[64 + lane];
    float4 w2 = w4[128 + lane];
    float4 w3 = w4[192 + lane];

    float acc[8];
    #pragma unroll
    for (int i = 0; i < 8; ++i) acc[i] = 0.f;

    #pragma unroll
    for (int i = 0; i < 8; ++i) {
        float4 a0 = xs[i * 256 + lane];
        float4 a1 = xs[i * 256 + 64 + lane];
        float4 a2 = xs[i * 256 + 128 + lane];
        float4 a3 = xs[i * 256 + 192 + lane];
        float r = w0.x * a0.x + w0.y * a0.y + w0.z * a0.z + w0.w * a0.w;
        r += w1.x * a1.x + w1.y * a1.y + w1.z * a1.z + w1.w * a1.w;
        r += w2.x * a2.x + w2.y * a2.y + w2.z * a2.z + w2.w * a2.w;
        r += w3.x * a3.x + w3.y * a3.y + w3.z * a3.z + w3.w * a3.w;
        acc[i] = r;
    }

    #pragma unroll
    for (int off = 32; off; off >>= 1) {
        #pragma unroll
        for (int i = 0; i < 8; ++i)
            acc[i] += __shfl_xor(acc[i], off, 64);
    }

    if (lane == 0) {
        const float bs = bias[e];
        #pragma unroll
        for (int i = 0; i < 8; ++i)
            y[(size_t)(bq * 8 + i) * E_DIM + e] = acc[i] + bs;
    }
}

// ---- Fused residual-add + LayerNorm: 16-lanes-per-row layout ---------------
// Wave handles 4 consecutive rows simultaneously: lane group g = lane>>4 owns
// row row0+g; lane's f4 slots are (lane&15) + 16*p, p=0..15. One load instr
// covers a 256 B slice of each of the 4 rows (full cache lines). Reduce =
// butterfly over strides 8,4,2,1 within the 16-lane group (4 shfl x 2 vals
// per 4 rows). y = img + a lives in 64 VGPRs between stats and apply.
// Grid: 2048 blocks x 256 thr, 16 rows/block.
__global__ __launch_bounds__(256) void resid_ln(
        const float* __restrict__ img,   // [B,S,E]
        const float* __restrict__ a,     // [B,E]
        const float* __restrict__ gamma, // [E]
        const float* __restrict__ beta,  // [E]
        float* __restrict__ out) {       // [B,S,E]
    const int t = threadIdx.x;
    const int wave = t >> 6;
    const int lane = t & 63;
    const int m = lane & 15;                        // lane within row group
    const int row = blockIdx.x * 16 + wave * 4 + (lane >> 4);
    const int b = row >> 10;                        // 16 | 1024: no straddle

    const float4* i4 = reinterpret_cast<const float4*>(img) + (size_t)row * 256;
    const float4* a4 = reinterpret_cast<const float4*>(a) + (size_t)b * 256;
    const float4* g4 = reinterpret_cast<const float4*>(gamma);
    const float4* b4 = reinterpret_cast<const float4*>(beta);
    float4* o4 = reinterpret_cast<float4*>(out) + (size_t)row * 256;

    // Phase A: issue all 16 independent img loads as one batch (16 KB/wave
    // in flight before any dependent arithmetic). Fence pins the batch.
    float4 y[16];
    #pragma unroll
    for (int p = 0; p < 16; ++p)
        y[p] = i4[m + 16 * p];
    __builtin_amdgcn_sched_barrier(0);

    // Residual add (a is L1/L2-hot broadcast) + partial sums.
    float s = 0.f, q = 0.f;
    #pragma unroll
    for (int p = 0; p < 16; ++p) {
        float4 av = a4[m + 16 * p];
        y[p].x += av.x;
        y[p].y += av.y;
        y[p].z += av.z;
        y[p].w += av.w;
        s += y[p].x + y[p].y + y[p].z + y[p].w;
        q += y[p].x * y[p].x + y[p].y * y[p].y
           + y[p].z * y[p].z + y[p].w * y[p].w;
    }

    // 4-stride butterfly within the 16-lane row group; every lane of the
    // group ends with the full row (s, q).
    #pragma unroll
    for (int off = 8; off; off >>= 1) {
        s += __shfl_xor(s, off, 64);
        q += __shfl_xor(q, off, 64);
    }
    const float mu   = s * (1.0f / E_DIM);
    const float rstd = rsqrtf(q * (1.0f / E_DIM) - mu * mu + 1e-5f);

    // Phase B: apply from registers; gamma/beta are L1-hot broadcasts.
    #pragma unroll
    for (int p = 0; p < 16; ++p) {
        float4 gv = g4[m + 16 * p];
        float4 bv = b4[m + 16 * p];
        float4 ov;
        ov.x = (y[p].x - mu) * rstd * gv.x + bv.x;
        ov.y = (y[p].y - mu) * rstd * gv.y + bv.y;
        ov.z = (y[p].z - mu) * rstd * gv.z + bv.z;
        ov.w = (y[p].w - mu) * rstd * gv.w + bv.w;
        o4[m + 16 * p] = ov;
    }
}

extern "C" void kernel_launch(void* const* d_in, const int* in_sizes, int n_in,
                              void* d_out, int out_size, void* d_ws, size_t ws_size,
                              hipStream_t stream) {
    // setup_inputs order:
    // 0 img_feat [B,S,E], 1 heat_feat [B,E], 2 W_img, 3 b_img, 4 W_heat, 5 b_heat,
    // 6 Wq, 7 bq, 8 Wk, 9 bk, 10 Wv, 11 bv, 12 Wo, 13 bo, 14 gamma, 15 beta
    const float* heat   = (const float*)d_in[1];
    const float* W_heat = (const float*)d_in[4];
    const float* b_heat = (const float*)d_in[5];
    const float* Wv     = (const float*)d_in[10];
    const float* bvv    = (const float*)d_in[11];
    const float* Wo     = (const float*)d_in[12];
    const float* bo     = (const float*)d_in[13];
    const float* img    = (const float*)d_in[0];
    const float* gamma  = (const float*)d_in[14];
    const float* beta   = (const float*)d_in[15];
    float* out = (float*)d_out;

    // Workspace: 3 fp32 [B,E] buffers = 384 KiB.
    float* ws = (float*)d_ws;
    float* tt = ws;                      // W_heat stage
    float* vv = ws + B_DIM * E_DIM;      // Wv stage
    float* aa = ws + 2 * B_DIM * E_DIM;  // Wo stage (attn_out rows)

    // 1024 blocks = 256 row-groups x 4 batch-quarters.
    gemv_xlds<<<1024, 256, 0, stream>>>(W_heat, b_heat, heat, tt);
    gemv_xlds<<<1024, 256, 0, stream>>>(Wv, bvv, tt, vv);
    gemv_xlds<<<1024, 256, 0, stream>>>(Wo, bo, vv, aa);

    // 2048 blocks x 256 thr; 16 rows/block (4 rows per wave, 16 lanes/row).
    resid_ln<<<(B_DIM * S_DIM) / 16, 256, 0, stream>>>(img, aa, gamma, beta, out);
}

// Round 9
// 290.202 us; speedup vs baseline: 1.0104x; 1.0104x over previous
//
#include <hip/hip_runtime.h>

// Problem constants (from reference): E=1024, H=16, D=64, B=32, S=1024.
// ALGEBRA: softmax over a length-1 key axis == 1.0 exactly, so attention
// collapses: attn_out[b,:] = Wo @ (Wv @ (W_heat @ heat[b] + b_heat) + bv) + bo
// (independent of s; the img projection / Q / K path is dead code).
// Final: out[b,s,:] = LayerNorm(img_feat[b,s,:] + a[b,:]) * gamma + beta.
// All tensors fp32.
//
// LN ledger (all ~82 us, 2.45 TB/s counted, FETCH ~64.6 MB):
//   r0 block-per-row / r3 wave-per-row / r4 3-buf pipeline (best, ~77) /
//   r5 split passes (worse) / r6 fenced 4-buf / r7 16-lane-per-row.
// Structure-invariance => the wall is the MEMORY IMAGE, not the kernel:
// img is only ~50% L3-resident, so HBM sees a swiss-cheese read stream +
// full write stream (2.45 TB/s vs 6.3-6.6 for clean streams).
// Single change vs r4 (289.9 best): NONTEMPORAL STORE on out. out is
// written every iteration and never read -- its L3 allocation only evicts
// img. NT store keeps img resident -> read hits rise.
// r8 lesson: __builtin_nontemporal_store rejects HIP float4 (class type);
// it requires a native vector -> ext_vector_type(4) alias for the store.

#define E_DIM 1024
#define B_DIM 32
#define S_DIM 1024

typedef float nvf4 __attribute__((ext_vector_type(4)));  // NT-store-legal

// ---- GEMV stage: y[b,e] = dot(W[e,:], x[b,:]) + bias[e] -------------------
// (unchanged from the passing round-3..7 version)
__global__ __launch_bounds__(256) void gemv_xlds(
        const float* __restrict__ W,    // [E,E] row-major
        const float* __restrict__ bias, // [E]
        const float* __restrict__ x,    // [B,E]
        float* __restrict__ y) {        // [B,E]
    __shared__ float4 xs[8 * 256];       // 8 batches x 1024 f32 = 32 KiB
    const int t = threadIdx.x;
    const int rg = blockIdx.x & 255;     // row group -> rows [rg*4, rg*4+4)
    const int bq = blockIdx.x >> 8;      // batch quarter -> batches [bq*8, ..+8)

    const float4* x4 = reinterpret_cast<const float4*>(x) + (size_t)bq * 8 * 256;
    #pragma unroll
    for (int i = 0; i < 8; ++i)
        xs[i * 256 + t] = x4[i * 256 + t];
    __syncthreads();

    const int wave = t >> 6;
    const int lane = t & 63;
    const int e = rg * 4 + wave;

    const float4* w4 = reinterpret_cast<const float4*>(W + (size_t)e * E_DIM);
    float4 w0 = w4[lane];
    float4 w1 = w4[64 + lane];
    float4 w2 = w4[128 + lane];
    float4 w3 = w4[192 + lane];

    float acc[8];
    #pragma unroll
    for (int i = 0; i < 8; ++i) acc[i] = 0.f;

    #pragma unroll
    for (int i = 0; i < 8; ++i) {
        float4 a0 = xs[i * 256 + lane];
        float4 a1 = xs[i * 256 + 64 + lane];
        float4 a2 = xs[i * 256 + 128 + lane];
        float4 a3 = xs[i * 256 + 192 + lane];
        float r = w0.x * a0.x + w0.y * a0.y + w0.z * a0.z + w0.w * a0.w;
        r += w1.x * a1.x + w1.y * a1.y + w1.z * a1.z + w1.w * a1.w;
        r += w2.x * a2.x + w2.y * a2.y + w2.z * a2.z + w2.w * a2.w;
        r += w3.x * a3.x + w3.y * a3.y + w3.z * a3.z + w3.w * a3.w;
        acc[i] = r;
    }

    #pragma unroll
    for (int off = 32; off; off >>= 1) {
        #pragma unroll
        for (int i = 0; i < 8; ++i)
            acc[i] += __shfl_xor(acc[i], off, 64);
    }

    if (lane == 0) {
        const float bs = bias[e];
        #pragma unroll
        for (int i = 0; i < 8; ++i)
            y[(size_t)(bq * 8 + i) * E_DIM + e] = acc[i] + bs;
    }
}

// ---- Fused residual-add + LayerNorm (r4 body + NT store) -------------------
// One wave per row, 8 rows/wave, 3-buffer rotation (2 rows in flight).
// a/gamma/beta register-cached per wave. Output stores are NONTEMPORAL
// via the ext_vector alias: out is never read, so letting it allocate in
// L3 only evicts img.
__global__ __launch_bounds__(256) void resid_ln(
        const float* __restrict__ img,   // [B,S,E]
        const float* __restrict__ a,     // [B,E]
        const float* __restrict__ gamma, // [E]
        const float* __restrict__ beta,  // [E]
        float* __restrict__ out) {       // [B,S,E]
    const int t = threadIdx.x;
    const int wave = t >> 6;
    const int lane = t & 63;
    const int row0 = blockIdx.x * 32 + wave * 8;   // 32 rows/block, 8/wave
    const int b = row0 >> 10;                      // 32 | 1024: no straddle

    const float4* g4  = reinterpret_cast<const float4*>(gamma);
    const float4* be4 = reinterpret_cast<const float4*>(beta);
    const float4* a4  = reinterpret_cast<const float4*>(a + (size_t)b * E_DIM);
    float4 gv[4], bv[4], av[4];
    #pragma unroll
    for (int p = 0; p < 4; ++p) {
        gv[p] = g4[p * 64 + lane];
        bv[p] = be4[p * 64 + lane];
        av[p] = a4[p * 64 + lane];
    }

    float4 xA[4], xB[4], xC[4];

#define LN_LOAD(X, rr)                                                        \
    {                                                                         \
        const float4* i4 =                                                    \
            reinterpret_cast<const float4*>(img + (size_t)(row0 + (rr)) * E_DIM); \
        X[0] = i4[lane];                                                      \
        X[1] = i4[64 + lane];                                                 \
        X[2] = i4[128 + lane];                                                \
        X[3] = i4[192 + lane];                                                \
    }

#define LN_PROC(X, rr)                                                        \
    {                                                                         \
        float4 y[4];                                                          \
        float s = 0.f, q = 0.f;                                               \
        _Pragma("unroll")                                                     \
        for (int p = 0; p < 4; ++p) {                                         \
            y[p].x = X[p].x + av[p].x;                                        \
            y[p].y = X[p].y + av[p].y;                                        \
            y[p].z = X[p].z + av[p].z;                                        \
            y[p].w = X[p].w + av[p].w;                                        \
            s += y[p].x + y[p].y + y[p].z + y[p].w;                           \
            q += y[p].x * y[p].x + y[p].y * y[p].y                            \
               + y[p].z * y[p].z + y[p].w * y[p].w;                           \
        }                                                                     \
        _Pragma("unroll")                                                     \
        for (int off = 32; off; off >>= 1) {                                  \
            s += __shfl_xor(s, off, 64);                                      \
            q += __shfl_xor(q, off, 64);                                      \
        }                                                                     \
        const float mu   = s * (1.0f / E_DIM);                                \
        const float rstd = rsqrtf(q * (1.0f / E_DIM) - mu * mu + 1e-5f);      \
        nvf4* o4 =                                                            \
            reinterpret_cast<nvf4*>(out + (size_t)(row0 + (rr)) * E_DIM);     \
        _Pragma("unroll")                                                     \
        for (int p = 0; p < 4; ++p) {                                         \
            nvf4 ov;                                                          \
            ov.x = (y[p].x - mu) * rstd * gv[p].x + bv[p].x;                  \
            ov.y = (y[p].y - mu) * rstd * gv[p].y + bv[p].y;                  \
            ov.z = (y[p].z - mu) * rstd * gv[p].z + bv[p].z;                  \
            ov.w = (y[p].w - mu) * rstd * gv[p].w + bv[p].w;                  \
            __builtin_nontemporal_store(ov, &o4[p * 64 + lane]);              \
        }                                                                     \
    }

    // 3-buffer rotation, 2 rows in flight ahead of each reduce.
    LN_LOAD(xA, 0)
    LN_LOAD(xB, 1)
    LN_LOAD(xC, 2) LN_PROC(xA, 0)
    LN_LOAD(xA, 3) LN_PROC(xB, 1)
    LN_LOAD(xB, 4) LN_PROC(xC, 2)
    LN_LOAD(xC, 5) LN_PROC(xA, 3)
    LN_LOAD(xA, 6) LN_PROC(xB, 4)
    LN_LOAD(xB, 7) LN_PROC(xC, 5)
    LN_PROC(xA, 6)
    LN_PROC(xB, 7)

#undef LN_LOAD
#undef LN_PROC
}

extern "C" void kernel_launch(void* const* d_in, const int* in_sizes, int n_in,
                              void* d_out, int out_size, void* d_ws, size_t ws_size,
                              hipStream_t stream) {
    // setup_inputs order:
    // 0 img_feat [B,S,E], 1 heat_feat [B,E], 2 W_img, 3 b_img, 4 W_heat, 5 b_heat,
    // 6 Wq, 7 bq, 8 Wk, 9 bk, 10 Wv, 11 bv, 12 Wo, 13 bo, 14 gamma, 15 beta
    const float* heat   = (const float*)d_in[1];
    const float* W_heat = (const float*)d_in[4];
    const float* b_heat = (const float*)d_in[5];
    const float* Wv     = (const float*)d_in[10];
    const float* bvv    = (const float*)d_in[11];
    const float* Wo     = (const float*)d_in[12];
    const float* bo     = (const float*)d_in[13];
    const float* img    = (const float*)d_in[0];
    const float* gamma  = (const float*)d_in[14];
    const float* beta   = (const float*)d_in[15];
    float* out = (float*)d_out;

    // Workspace: 3 fp32 [B,E] buffers = 384 KiB.
    float* ws = (float*)d_ws;
    float* tt = ws;                      // W_heat stage
    float* vv = ws + B_DIM * E_DIM;      // Wv stage
    float* aa = ws + 2 * B_DIM * E_DIM;  // Wo stage (attn_out rows)

    // 1024 blocks = 256 row-groups x 4 batch-quarters.
    gemv_xlds<<<1024, 256, 0, stream>>>(W_heat, b_heat, heat, tt);
    gemv_xlds<<<1024, 256, 0, stream>>>(Wv, bvv, tt, vv);
    gemv_xlds<<<1024, 256, 0, stream>>>(Wo, bo, vv, aa);

    // 1024 blocks x 256 thr; 32 rows/block (8 rows/wave, 3-buffer pipeline).
    resid_ln<<<(B_DIM * S_DIM) / 32, 256, 0, stream>>>(img, aa, gamma, beta, out);
}

// Round 10
// 278.907 us; speedup vs baseline: 1.0513x; 1.0405x over previous
//
#include <hip/hip_runtime.h>

// Problem constants (from reference): E=1024, H=16, D=64, B=32, S=1024.
// ALGEBRA: softmax over a length-1 key axis == 1.0 exactly, so attention
// collapses: attn_out[b,:] = Wo @ (Wv @ (W_heat @ heat[b] + b_heat) + bv) + bo
// (independent of s; the img projection / Q / K path is dead code).
// Final: out[b,s,:] = LayerNorm(img_feat[b,s,:] + a[b,:]) * gamma + beta.
// All tensors fp32.
//
// LN ledger (all ~80-84 us, 2.45 TB/s counted, FETCH ~64.6 MB):
//   r0 block-per-row / r3 wave-per-row / r4 3-buf pipeline / r5 split
//   passes (worse) / r6 fenced 4-buf / r7 16-lane-per-row / r9 NT-store
//   (neutral: FETCH unchanged => write-side L3 pollution theory DEAD).
// Remaining theory: the 50%-L3-resident img makes the HBM read stream a
// scattered "swiss cheese" of isolated line misses + a write stream ->
// poor DRAM locality, 2.45 TB/s (clean streams: 6.3-6.6 TB/s on this chip;
// m219's LN runs at 82% BW). This round: NONTEMPORAL LOAD on img (+NT
// store kept) -> bypass L3 allocation, clean fully-missing read stream.
// Expected: FETCH 64.6 -> ~128 MB; if theory holds, LN 80 -> 50-60 us.
// If FETCH doubles but dur doesn't drop: machine ceiling, declare roofline.

#define E_DIM 1024
#define B_DIM 32
#define S_DIM 1024

typedef float nvf4 __attribute__((ext_vector_type(4)));  // NT-builtin-legal

// ---- GEMV stage: y[b,e] = dot(W[e,:], x[b,:]) + bias[e] -------------------
// (unchanged from the passing round-3..9 version)
__global__ __launch_bounds__(256) void gemv_xlds(
        const float* __restrict__ W,    // [E,E] row-major
        const float* __restrict__ bias, // [E]
        const float* __restrict__ x,    // [B,E]
        float* __restrict__ y) {        // [B,E]
    __shared__ float4 xs[8 * 256];       // 8 batches x 1024 f32 = 32 KiB
    const int t = threadIdx.x;
    const int rg = blockIdx.x & 255;     // row group -> rows [rg*4, rg*4+4)
    const int bq = blockIdx.x >> 8;      // batch quarter -> batches [bq*8, ..+8)

    const float4* x4 = reinterpret_cast<const float4*>(x) + (size_t)bq * 8 * 256;
    #pragma unroll
    for (int i = 0; i < 8; ++i)
        xs[i * 256 + t] = x4[i * 256 + t];
    __syncthreads();

    const int wave = t >> 6;
    const int lane = t & 63;
    const int e = rg * 4 + wave;

    const float4* w4 = reinterpret_cast<const float4*>(W + (size_t)e * E_DIM);
    float4 w0 = w4[lane];
    float4 w1 = w4[64 + lane];
    float4 w2 = w4[128 + lane];
    float4 w3 = w4[192 + lane];

    float acc[8];
    #pragma unroll
    for (int i = 0; i < 8; ++i) acc[i] = 0.f;

    #pragma unroll
    for (int i = 0; i < 8; ++i) {
        float4 a0 = xs[i * 256 + lane];
        float4 a1 = xs[i * 256 + 64 + lane];
        float4 a2 = xs[i * 256 + 128 + lane];
        float4 a3 = xs[i * 256 + 192 + lane];
        float r = w0.x * a0.x + w0.y * a0.y + w0.z * a0.z + w0.w * a0.w;
        r += w1.x * a1.x + w1.y * a1.y + w1.z * a1.z + w1.w * a1.w;
        r += w2.x * a2.x + w2.y * a2.y + w2.z * a2.z + w2.w * a2.w;
        r += w3.x * a3.x + w3.y * a3.y + w3.z * a3.z + w3.w * a3.w;
        acc[i] = r;
    }

    #pragma unroll
    for (int off = 32; off; off >>= 1) {
        #pragma unroll
        for (int i = 0; i < 8; ++i)
            acc[i] += __shfl_xor(acc[i], off, 64);
    }

    if (lane == 0) {
        const float bs = bias[e];
        #pragma unroll
        for (int i = 0; i < 8; ++i)
            y[(size_t)(bq * 8 + i) * E_DIM + e] = acc[i] + bs;
    }
}

// ---- Fused residual-add + LayerNorm (r4 body + NT load + NT store) ---------
// One wave per row, 8 rows/wave, 3-buffer rotation (2 rows in flight).
// a/gamma/beta register-cached per wave. img loads and out stores are both
// NONTEMPORAL: neither stream allocates in cache -> two clean HBM streams.
__global__ __launch_bounds__(256) void resid_ln(
        const float* __restrict__ img,   // [B,S,E]
        const float* __restrict__ a,     // [B,E]
        const float* __restrict__ gamma, // [E]
        const float* __restrict__ beta,  // [E]
        float* __restrict__ out) {       // [B,S,E]
    const int t = threadIdx.x;
    const int wave = t >> 6;
    const int lane = t & 63;
    const int row0 = blockIdx.x * 32 + wave * 8;   // 32 rows/block, 8/wave
    const int b = row0 >> 10;                      // 32 | 1024: no straddle

    const float4* g4  = reinterpret_cast<const float4*>(gamma);
    const float4* be4 = reinterpret_cast<const float4*>(beta);
    const float4* a4  = reinterpret_cast<const float4*>(a + (size_t)b * E_DIM);
    float4 gv[4], bv[4], av[4];
    #pragma unroll
    for (int p = 0; p < 4; ++p) {
        gv[p] = g4[p * 64 + lane];
        bv[p] = be4[p * 64 + lane];
        av[p] = a4[p * 64 + lane];
    }

    nvf4 xA[4], xB[4], xC[4];

#define LN_LOAD(X, rr)                                                        \
    {                                                                         \
        const nvf4* i4 =                                                      \
            reinterpret_cast<const nvf4*>(img + (size_t)(row0 + (rr)) * E_DIM); \
        X[0] = __builtin_nontemporal_load(&i4[lane]);                         \
        X[1] = __builtin_nontemporal_load(&i4[64 + lane]);                    \
        X[2] = __builtin_nontemporal_load(&i4[128 + lane]);                   \
        X[3] = __builtin_nontemporal_load(&i4[192 + lane]);                   \
    }

#define LN_PROC(X, rr)                                                        \
    {                                                                         \
        float yx[4], yy[4], yz[4], yw[4];                                     \
        float s = 0.f, q = 0.f;                                               \
        _Pragma("unroll")                                                     \
        for (int p = 0; p < 4; ++p) {                                         \
            yx[p] = X[p].x + av[p].x;                                         \
            yy[p] = X[p].y + av[p].y;                                         \
            yz[p] = X[p].z + av[p].z;                                         \
            yw[p] = X[p].w + av[p].w;                                         \
            s += yx[p] + yy[p] + yz[p] + yw[p];                               \
            q += yx[p] * yx[p] + yy[p] * yy[p]                                \
               + yz[p] * yz[p] + yw[p] * yw[p];                               \
        }                                                                     \
        _Pragma("unroll")                                                     \
        for (int off = 32; off; off >>= 1) {                                  \
            s += __shfl_xor(s, off, 64);                                      \
            q += __shfl_xor(q, off, 64);                                      \
        }                                                                     \
        const float mu   = s * (1.0f / E_DIM);                                \
        const float rstd = rsqrtf(q * (1.0f / E_DIM) - mu * mu + 1e-5f);      \
        nvf4* o4 =                                                            \
            reinterpret_cast<nvf4*>(out + (size_t)(row0 + (rr)) * E_DIM);     \
        _Pragma("unroll")                                                     \
        for (int p = 0; p < 4; ++p) {                                         \
            nvf4 ov;                                                          \
            ov.x = (yx[p] - mu) * rstd * gv[p].x + bv[p].x;                   \
            ov.y = (yy[p] - mu) * rstd * gv[p].y + bv[p].y;                   \
            ov.z = (yz[p] - mu) * rstd * gv[p].z + bv[p].z;                   \
            ov.w = (yw[p] - mu) * rstd * gv[p].w + bv[p].w;                   \
            __builtin_nontemporal_store(ov, &o4[p * 64 + lane]);              \
        }                                                                     \
    }

    // 3-buffer rotation, 2 rows in flight ahead of each reduce.
    LN_LOAD(xA, 0)
    LN_LOAD(xB, 1)
    LN_LOAD(xC, 2) LN_PROC(xA, 0)
    LN_LOAD(xA, 3) LN_PROC(xB, 1)
    LN_LOAD(xB, 4) LN_PROC(xC, 2)
    LN_LOAD(xC, 5) LN_PROC(xA, 3)
    LN_LOAD(xA, 6) LN_PROC(xB, 4)
    LN_LOAD(xB, 7) LN_PROC(xC, 5)
    LN_PROC(xA, 6)
    LN_PROC(xB, 7)

#undef LN_LOAD
#undef LN_PROC
}

extern "C" void kernel_launch(void* const* d_in, const int* in_sizes, int n_in,
                              void* d_out, int out_size, void* d_ws, size_t ws_size,
                              hipStream_t stream) {
    // setup_inputs order:
    // 0 img_feat [B,S,E], 1 heat_feat [B,E], 2 W_img, 3 b_img, 4 W_heat, 5 b_heat,
    // 6 Wq, 7 bq, 8 Wk, 9 bk, 10 Wv, 11 bv, 12 Wo, 13 bo, 14 gamma, 15 beta
    const float* heat   = (const float*)d_in[1];
    const float* W_heat = (const float*)d_in[4];
    const float* b_heat = (const float*)d_in[5];
    const float* Wv     = (const float*)d_in[10];
    const float* bvv    = (const float*)d_in[11];
    const float* Wo     = (const float*)d_in[12];
    const float* bo     = (const float*)d_in[13];
    const float* img    = (const float*)d_in[0];
    const float* gamma  = (const float*)d_in[14];
    const float* beta   = (const float*)d_in[15];
    float* out = (float*)d_out;

    // Workspace: 3 fp32 [B,E] buffers = 384 KiB.
    float* ws = (float*)d_ws;
    float* tt = ws;                      // W_heat stage
    float* vv = ws + B_DIM * E_DIM;      // Wv stage
    float* aa = ws + 2 * B_DIM * E_DIM;  // Wo stage (attn_out rows)

    // 1024 blocks = 256 row-groups x 4 batch-quarters.
    gemv_xlds<<<1024, 256, 0, stream>>>(W_heat, b_heat, heat, tt);
    gemv_xlds<<<1024, 256, 0, stream>>>(Wv, bvv, tt, vv);
    gemv_xlds<<<1024, 256, 0, stream>>>(Wo, bo, vv, aa);

    // 1024 blocks x 256 thr; 32 rows/block (8 rows/wave, 3-buffer pipeline).
    resid_ln<<<(B_DIM * S_DIM) / 32, 256, 0, stream>>>(img, aa, gamma, beta, out);
}